// Round 3
// baseline (4782.529 us; speedup 1.0000x reference)
//
#include <hip/hip_runtime.h>
#include <hip/hip_bf16.h>

#define B 64
#define KDIM 196
#define H 512
#define E 512
#define V 10000
#define TSTEPS 30
#define VP 10048   // padded V: 157*64
#define NVC 40     // ceil(V/256) argmax chunks

// ---------------- precompute kernels ----------------

// dst[i][v] = fc_w[v][coloff + i], i in [0,512), v in [0,VP) (zero-padded)
__global__ void k_transpose_fc(const float* __restrict__ fcw, float* __restrict__ dst, int coloff) {
    __shared__ float tile[32][33];
    int v0 = blockIdx.x * 32, i0 = blockIdx.y * 32;
    int tx = threadIdx.x, ty = threadIdx.y;
#pragma unroll
    for (int r = 0; r < 32; r += 8) {
        int v = v0 + ty + r; int i = i0 + tx;
        tile[ty + r][tx] = (v < V) ? fcw[(size_t)v * 1024 + coloff + i] : 0.f;
    }
    __syncthreads();
#pragma unroll
    for (int r = 0; r < 32; r += 8) {
        int i = i0 + ty + r; int v = v0 + tx;
        dst[(size_t)i * VP + v] = tile[tx][ty + r];
    }
}

// WcT[i][j] = (i<512) ? wih[j][i] : whh[j][i-512];  i<1024, j<2048
__global__ void k_build_wct(const float* __restrict__ wih, const float* __restrict__ whh,
                            float* __restrict__ dst) {
    __shared__ float tile[32][33];
    int j0 = blockIdx.x * 32, i0 = blockIdx.y * 32;
    int tx = threadIdx.x, ty = threadIdx.y;
#pragma unroll
    for (int r = 0; r < 32; r += 8) {
        int j = j0 + ty + r; int i = i0 + tx;
        tile[ty + r][tx] = (i < 512) ? wih[(size_t)j * 512 + i] : whh[(size_t)j * 512 + i - 512];
    }
    __syncthreads();
#pragma unroll
    for (int r = 0; r < 32; r += 8) {
        int i = i0 + ty + r; int j = j0 + tx;
        dst[(size_t)i * 2048 + j] = tile[tx][ty + r];
    }
}

// mean over K per (b,h) row; one wave per row
__global__ void k_mean(const float* __restrict__ iml, float* __restrict__ mean) {
    int w = threadIdx.x >> 6, lane = threadIdx.x & 63;
    int row = blockIdx.x * 4 + w;             // row = b*512 + h
    const float* p = iml + (size_t)row * KDIM;
    float s = p[lane] + p[lane + 64] + p[lane + 128] + ((lane < 4) ? p[lane + 192] : 0.f);
#pragma unroll
    for (int off = 32; off; off >>= 1) s += __shfl_down(s, off);
    if (lane == 0) mean[row] = s * (1.f / 196.f);
}

// alpha[b][k] = softmax_k( sum_h iml[b][h][k] * attn_w[h] )   (shift-invariance: h@w_h + attn_b dropped)
__global__ void k_e_alpha(const float* __restrict__ iml, const float* __restrict__ attn_w,
                          float* __restrict__ alpha) {
    int b = blockIdx.x, t = threadIdx.x;
    __shared__ float wa[512];
    wa[t] = attn_w[t]; wa[t + 256] = attn_w[t + 256];
    __syncthreads();
    float acc = 0.f;
    if (t < KDIM) {
        const float* p = iml + (size_t)b * 512 * KDIM + t;
#pragma unroll 8
        for (int h = 0; h < 512; ++h) acc += p[(size_t)h * KDIM] * wa[h];
    }
    __shared__ float red[256];
    red[t] = (t < KDIM) ? acc : -INFINITY;
    __syncthreads();
    for (int s = 128; s; s >>= 1) { if (t < s) red[t] = fmaxf(red[t], red[t + s]); __syncthreads(); }
    float mx = red[0];
    __syncthreads();
    float ex = (t < KDIM) ? expf(acc - mx) : 0.f;
    red[t] = ex; __syncthreads();
    for (int s = 128; s; s >>= 1) { if (t < s) red[t] += red[t + s]; __syncthreads(); }
    if (t < KDIM) alpha[b * KDIM + t] = ex / red[0];
}

// cs[b][h] = sum_k alpha[b][k] * iml[b][h][k]; one wave per row
__global__ void k_cs(const float* __restrict__ iml, const float* __restrict__ alpha,
                     float* __restrict__ cs) {
    int w = threadIdx.x >> 6, lane = threadIdx.x & 63;
    int row = blockIdx.x * 4 + w;
    int b = row >> 9;
    const float* p = iml + (size_t)row * KDIM;
    const float* al = alpha + b * KDIM;
    float s = p[lane] * al[lane] + p[lane + 64] * al[lane + 64] + p[lane + 128] * al[lane + 128]
            + ((lane < 4) ? p[lane + 192] * al[lane + 192] : 0.f);
#pragma unroll
    for (int off = 32; off; off >>= 1) s += __shfl_down(s, off);
    if (lane == 0) cs[row] = s;
}

// out[b][j] = relu(bias[j] + sum_i in[b][i] * W[j][i]); (64x512)@(512x512)
__global__ void k_dense_relu(const float* __restrict__ in, const float* __restrict__ W,
                             const float* __restrict__ bias, float* __restrict__ out) {
    int b = blockIdx.y; int j = blockIdx.x * 256 + threadIdx.x;
    __shared__ float xs[512];
    xs[threadIdx.x] = in[b * 512 + threadIdx.x];
    xs[threadIdx.x + 256] = in[b * 512 + threadIdx.x + 256];
    __syncthreads();
    float acc = bias[j];
    const float4* w4 = (const float4*)(W + (size_t)j * 512);
#pragma unroll 4
    for (int i4 = 0; i4 < 128; ++i4) {
        float4 w = w4[i4];
        float4 x = *(const float4*)&xs[i4 * 4];
        acc += w.x * x.x + w.y * x.y + w.z * x.z + w.w * x.w;
    }
    out[b * 512 + j] = fmaxf(acc, 0.f);
}

// ---------------- per-step kernels ----------------

// part[kc][b][v] = sum_{i in chunk kc} A[b][i] * Wt[i][v];  A:(64x512), Wt rows i, width VP
__global__ void k_gemmA(const float* __restrict__ A, const float* __restrict__ Wt,
                        float* __restrict__ part) {
    const int WN = VP;
    int j0 = blockIdx.x * 64;
    int kc = blockIdx.y;          // 0..1, chunks of 256
    int k0 = kc * 256;
    int t = threadIdx.x;
    int tv = t & 31, tb = t >> 5;
    __shared__ float a_s[64 * 68];
    float2 acc[8];
#pragma unroll
    for (int u = 0; u < 8; ++u) acc[u] = make_float2(0.f, 0.f);
    for (int kt = 0; kt < 4; ++kt) {
        __syncthreads();
#pragma unroll
        for (int p = 0; p < 16; ++p) {
            int e = p * 256 + t; int bb = e >> 6; int ii = e & 63;
            a_s[ii * 68 + bb] = A[bb * 512 + k0 + kt * 64 + ii];
        }
        __syncthreads();
        const float* wrow = Wt + (size_t)(k0 + kt * 64) * WN + j0 + tv * 2;
#pragma unroll 8
        for (int ii = 0; ii < 64; ++ii) {
            float2 w = *(const float2*)(wrow + (size_t)ii * WN);
            float4 a0 = *(const float4*)&a_s[ii * 68 + tb * 8];
            float4 a1 = *(const float4*)&a_s[ii * 68 + tb * 8 + 4];
            acc[0].x += a0.x * w.x; acc[0].y += a0.x * w.y;
            acc[1].x += a0.y * w.x; acc[1].y += a0.y * w.y;
            acc[2].x += a0.z * w.x; acc[2].y += a0.z * w.y;
            acc[3].x += a0.w * w.x; acc[3].y += a0.w * w.y;
            acc[4].x += a1.x * w.x; acc[4].y += a1.x * w.y;
            acc[5].x += a1.y * w.x; acc[5].y += a1.y * w.y;
            acc[6].x += a1.z * w.x; acc[6].y += a1.z * w.y;
            acc[7].x += a1.w * w.x; acc[7].y += a1.w * w.y;
        }
    }
#pragma unroll
    for (int u = 0; u < 8; ++u) {
        int bb = tb * 8 + u;
        *(float2*)&part[(size_t)(kc * 64 + bb) * WN + j0 + tv * 2] = acc[u];
    }
}

// LSTM gates GEMM: xh = [x | h], x = t0 ? img : emb[sample]; part[kc][b][j], j<2048
__global__ void k_lstm_gemm(const float* __restrict__ img, const float* __restrict__ emb,
                            const int* __restrict__ smp, const float* __restrict__ hbuf,
                            const float* __restrict__ WcT, float* __restrict__ part, int t0) {
    const int WN = 2048;
    int j0 = blockIdx.x * 64;
    int kc = blockIdx.y;          // 0..3, chunks of 256
    int k0 = kc * 256;
    int t = threadIdx.x;
    int tv = t & 31, tb = t >> 5;
    __shared__ float a_s[64 * 68];
    float2 acc[8];
#pragma unroll
    for (int u = 0; u < 8; ++u) acc[u] = make_float2(0.f, 0.f);
    for (int kt = 0; kt < 4; ++kt) {
        __syncthreads();
#pragma unroll
        for (int p = 0; p < 16; ++p) {
            int e = p * 256 + t; int bb = e >> 6; int ii = e & 63;
            int gi = k0 + kt * 64 + ii;
            float v;
            if (gi < 512) v = t0 ? img[bb * 512 + gi] : emb[(size_t)smp[bb] * 512 + gi];
            else          v = hbuf[bb * 512 + gi - 512];
            a_s[ii * 68 + bb] = v;
        }
        __syncthreads();
        const float* wrow = WcT + (size_t)(k0 + kt * 64) * WN + j0 + tv * 2;
#pragma unroll 8
        for (int ii = 0; ii < 64; ++ii) {
            float2 w = *(const float2*)(wrow + (size_t)ii * WN);
            float4 a0 = *(const float4*)&a_s[ii * 68 + tb * 8];
            float4 a1 = *(const float4*)&a_s[ii * 68 + tb * 8 + 4];
            acc[0].x += a0.x * w.x; acc[0].y += a0.x * w.y;
            acc[1].x += a0.y * w.x; acc[1].y += a0.y * w.y;
            acc[2].x += a0.z * w.x; acc[2].y += a0.z * w.y;
            acc[3].x += a0.w * w.x; acc[3].y += a0.w * w.y;
            acc[4].x += a1.x * w.x; acc[4].y += a1.x * w.y;
            acc[5].x += a1.y * w.x; acc[5].y += a1.y * w.y;
            acc[6].x += a1.z * w.x; acc[6].y += a1.z * w.y;
            acc[7].x += a1.w * w.x; acc[7].y += a1.w * w.y;
        }
    }
#pragma unroll
    for (int u = 0; u < 8; ++u) {
        int bb = tb * 8 + u;
        *(float2*)&part[(size_t)(kc * 64 + bb) * WN + j0 + tv * 2] = acc[u];
    }
}

// reduce split-K partials, apply biases+gates, update h,c (in place)
__global__ void k_gates(const float* __restrict__ part, const float* __restrict__ bih,
                        const float* __restrict__ bhh, float* __restrict__ hbuf,
                        float* __restrict__ cbuf) {
    int e = blockIdx.x * 256 + threadIdx.x;   // e = b*512 + jj
    int b = e >> 9, jj = e & 511;
    float g[4];
#pragma unroll
    for (int gg = 0; gg < 4; ++gg) {
        int j = jj + gg * 512;
        float s = bih[j] + bhh[j];
#pragma unroll
        for (int kc = 0; kc < 4; ++kc) s += part[(size_t)(kc * 64 + b) * 2048 + j];
        g[gg] = s;
    }
    float ig = 1.f / (1.f + expf(-g[0]));
    float fg = 1.f / (1.f + expf(-g[1]));
    float gt = tanhf(g[2]);
    float og = 1.f / (1.f + expf(-g[3]));
    float c = fg * cbuf[e] + ig * gt;
    float h = og * tanhf(c);
    cbuf[e] = c; hbuf[e] = h;
}

// base[b][v] = lpart0 + lpart1 + fc_b[v]
__global__ void k_base_finish(const float* __restrict__ lpart, const float* __restrict__ fc_b,
                              float* __restrict__ base) {
    int b = blockIdx.y; int v = blockIdx.x * 256 + threadIdx.x;
    if (v < V) base[(size_t)b * VP + v] = lpart[(size_t)b * VP + v] + lpart[(size_t)(64 + b) * VP + v] + fc_b[v];
}

// logits = lpart0 + lpart1 + base; write f32 out; per-(b,chunk) argmax partial
__global__ void k_logits_finish(const float* __restrict__ lpart, const float* __restrict__ base,
                                float* __restrict__ out0, float* __restrict__ amaxv,
                                int* __restrict__ amaxi, int t) {
    int b = blockIdx.y, vc = blockIdx.x, tid = threadIdx.x;
    int v = vc * 256 + tid;
    float val = -INFINITY;
    if (v < V) {
        val = lpart[(size_t)b * VP + v] + lpart[(size_t)(64 + b) * VP + v] + base[(size_t)b * VP + v];
        out0[((size_t)b * TSTEPS + t) * V + v] = val;
    }
    __shared__ float sv[256]; __shared__ int si[256];
    sv[tid] = val; si[tid] = (v < V) ? v : 0x7fffffff;
    __syncthreads();
    for (int s = 128; s; s >>= 1) {
        if (tid < s) {
            if (sv[tid + s] > sv[tid] || (sv[tid + s] == sv[tid] && si[tid + s] < si[tid])) {
                sv[tid] = sv[tid + s]; si[tid] = si[tid + s];
            }
        }
        __syncthreads();
    }
    if (tid == 0) { amaxv[b * NVC + vc] = sv[0]; amaxi[b * NVC + vc] = si[0]; }
}

__global__ void k_argmax_final(const float* __restrict__ amaxv, const int* __restrict__ amaxi,
                               int* __restrict__ smp, float* __restrict__ out1, int t) {
    int b = threadIdx.x;
    if (b < B) {
        float best = -INFINITY; int bi = 0x7fffffff;
        for (int vc = 0; vc < NVC; ++vc) {
            float v = amaxv[b * NVC + vc];
            if (v > best) { best = v; bi = amaxi[b * NVC + vc]; }
        }
        smp[b] = bi;
        out1[b * TSTEPS + t] = (float)bi;
    }
}

// ---------------- launch ----------------

extern "C" void kernel_launch(void* const* d_in, const int* in_sizes, int n_in,
                              void* d_out, int out_size, void* d_ws, size_t ws_size,
                              hipStream_t stream) {
    const float* iml   = (const float*)d_in[0];
    const float* img   = (const float*)d_in[1];
    const float* m1w1  = (const float*)d_in[2];
    const float* m1b1  = (const float*)d_in[3];
    const float* m1w2  = (const float*)d_in[4];
    const float* m1b2  = (const float*)d_in[5];
    const float* m2w1  = (const float*)d_in[6];
    const float* m2b1  = (const float*)d_in[7];
    const float* m2w2  = (const float*)d_in[8];
    const float* m2b2  = (const float*)d_in[9];
    const float* wih   = (const float*)d_in[10];
    const float* whh   = (const float*)d_in[11];
    const float* bih   = (const float*)d_in[12];
    const float* bhh   = (const float*)d_in[13];
    const float* attnw = (const float*)d_in[14];
    const float* fcw   = (const float*)d_in[16];
    const float* fcb   = (const float*)d_in[17];
    const float* emb   = (const float*)d_in[18];

    float* out0 = (float*)d_out;                        // logits (B, T, V) f32
    float* out1 = out0 + (size_t)B * TSTEPS * V;        // samples (B, T) as f32

    float* ws = (float*)d_ws;
    size_t off = 0;
    float* fcT   = ws + off; off += (size_t)512 * VP;       // 5,144,576
    float* WcT   = ws + off; off += (size_t)1024 * 2048;    // 2,097,152
    float* base  = ws + off; off += (size_t)B * VP;
    float* lpart = ws + off; off += (size_t)2 * B * VP;
    float* gpart = ws + off; off += (size_t)4 * B * 2048;
    float* meanb = ws + off; off += B * 512;
    float* alpha = ws + off; off += B * KDIM;
    float* csb   = ws + off; off += B * 512;
    float* tmpb  = ws + off; off += B * 512;
    float* hbuf  = ws + off; off += B * 512;
    float* cbuf  = ws + off; off += B * 512;
    float* amaxv = ws + off; off += B * NVC;
    int*   amaxi = (int*)(ws + off); off += B * NVC;
    int*   smp   = (int*)(ws + off); off += B;

    // smp sits in poisoned ws; ensure any speculative emb[smp[b]] access at t=0
    // is in-bounds (stream-ordered, graph-capture-safe)
    hipMemsetAsync(smp, 0, B * sizeof(int), stream);

    // ---- precompute ----
    k_mean<<<dim3(8192), dim3(256), 0, stream>>>(iml, meanb);
    k_e_alpha<<<dim3(64), dim3(256), 0, stream>>>(iml, attnw, alpha);
    k_cs<<<dim3(8192), dim3(256), 0, stream>>>(iml, alpha, csb);
    k_dense_relu<<<dim3(2, 64), dim3(256), 0, stream>>>(meanb, m1w1, m1b1, tmpb);
    k_dense_relu<<<dim3(2, 64), dim3(256), 0, stream>>>(tmpb, m1w2, m1b2, hbuf);
    k_dense_relu<<<dim3(2, 64), dim3(256), 0, stream>>>(meanb, m2w1, m2b1, tmpb);
    k_dense_relu<<<dim3(2, 64), dim3(256), 0, stream>>>(tmpb, m2w2, m2b2, cbuf);

    // base logits from cs using transpose of fc_w cols [512,1024)
    k_transpose_fc<<<dim3(VP / 32, 16), dim3(32, 8), 0, stream>>>(fcw, fcT, 512);
    k_gemmA<<<dim3(157, 2), dim3(256), 0, stream>>>(csb, fcT, lpart);
    k_base_finish<<<dim3(NVC, 64), dim3(256), 0, stream>>>(lpart, fcb, base);
    // now overwrite fcT with transpose of fc_w cols [0,512) for the step loop
    k_transpose_fc<<<dim3(VP / 32, 16), dim3(32, 8), 0, stream>>>(fcw, fcT, 0);
    k_build_wct<<<dim3(64, 32), dim3(32, 8), 0, stream>>>(wih, whh, WcT);

    // ---- decode loop ----
    for (int t = 0; t < TSTEPS; ++t) {
        k_lstm_gemm<<<dim3(32, 4), dim3(256), 0, stream>>>(img, emb, smp, hbuf, WcT, gpart, (t == 0) ? 1 : 0);
        k_gates<<<dim3(128), dim3(256), 0, stream>>>(gpart, bih, bhh, hbuf, cbuf);
        k_gemmA<<<dim3(157, 2), dim3(256), 0, stream>>>(hbuf, fcT, lpart);
        k_logits_finish<<<dim3(NVC, 64), dim3(256), 0, stream>>>(lpart, base, out0, amaxv, amaxi, t);
        k_argmax_final<<<dim3(1), dim3(64), 0, stream>>>(amaxv, amaxi, smp, out1, t);
    }
}

// Round 4
// 1223.071 us; speedup vs baseline: 3.9103x; 3.9103x over previous
//
#include <hip/hip_runtime.h>
#include <hip/hip_bf16.h>

#define B 64
#define KDIM 196
#define H 512
#define E 512
#define V 10000
#define TSTEPS 30
#define VP 10240   // padded V: 40*256
#define NVC 40     // 10240/256 argmax chunks

// ---------------- precompute kernels ----------------

// dst[i][v] = fc_w[v][coloff + i], i in [0,512), v in [0,VP) (zero-padded)
__global__ void k_transpose_fc(const float* __restrict__ fcw, float* __restrict__ dst, int coloff) {
    __shared__ float tile[32][33];
    int v0 = blockIdx.x * 32, i0 = blockIdx.y * 32;
    int tx = threadIdx.x, ty = threadIdx.y;
#pragma unroll
    for (int r = 0; r < 32; r += 8) {
        int v = v0 + ty + r; int i = i0 + tx;
        tile[ty + r][tx] = (v < V) ? fcw[(size_t)v * 1024 + coloff + i] : 0.f;
    }
    __syncthreads();
#pragma unroll
    for (int r = 0; r < 32; r += 8) {
        int i = i0 + ty + r; int v = v0 + tx;
        dst[(size_t)i * VP + v] = tile[tx][ty + r];
    }
}

// WcT[i][j] = (i<512) ? wih[j][i] : whh[j][i-512];  i<1024, j<2048
__global__ void k_build_wct(const float* __restrict__ wih, const float* __restrict__ whh,
                            float* __restrict__ dst) {
    __shared__ float tile[32][33];
    int j0 = blockIdx.x * 32, i0 = blockIdx.y * 32;
    int tx = threadIdx.x, ty = threadIdx.y;
#pragma unroll
    for (int r = 0; r < 32; r += 8) {
        int j = j0 + ty + r; int i = i0 + tx;
        tile[ty + r][tx] = (i < 512) ? wih[(size_t)j * 512 + i] : whh[(size_t)j * 512 + i - 512];
    }
    __syncthreads();
#pragma unroll
    for (int r = 0; r < 32; r += 8) {
        int i = i0 + ty + r; int j = j0 + tx;
        dst[(size_t)i * 2048 + j] = tile[tx][ty + r];
    }
}

// mean over K per (b,h) row; one wave per row
__global__ void k_mean(const float* __restrict__ iml, float* __restrict__ mean) {
    int w = threadIdx.x >> 6, lane = threadIdx.x & 63;
    int row = blockIdx.x * 4 + w;             // row = b*512 + h
    const float* p = iml + (size_t)row * KDIM;
    float s = p[lane] + p[lane + 64] + p[lane + 128] + ((lane < 4) ? p[lane + 192] : 0.f);
#pragma unroll
    for (int off = 32; off; off >>= 1) s += __shfl_down(s, off);
    if (lane == 0) mean[row] = s * (1.f / 196.f);
}

// alpha[b][k] = softmax_k( sum_h iml[b][h][k] * attn_w[h] )   (shift-invariance: h@w_h + attn_b dropped)
__global__ void k_e_alpha(const float* __restrict__ iml, const float* __restrict__ attn_w,
                          float* __restrict__ alpha) {
    int b = blockIdx.x, t = threadIdx.x;
    __shared__ float wa[512];
    wa[t] = attn_w[t]; wa[t + 256] = attn_w[t + 256];
    __syncthreads();
    float acc = 0.f;
    if (t < KDIM) {
        const float* p = iml + (size_t)b * 512 * KDIM + t;
#pragma unroll 8
        for (int h = 0; h < 512; ++h) acc += p[(size_t)h * KDIM] * wa[h];
    }
    __shared__ float red[256];
    red[t] = (t < KDIM) ? acc : -__builtin_inff();
    __syncthreads();
    for (int s = 128; s; s >>= 1) { if (t < s) red[t] = fmaxf(red[t], red[t + s]); __syncthreads(); }
    float mx = red[0];
    __syncthreads();
    float ex = (t < KDIM) ? expf(acc - mx) : 0.f;
    red[t] = ex; __syncthreads();
    for (int s = 128; s; s >>= 1) { if (t < s) red[t] += red[t + s]; __syncthreads(); }
    if (t < KDIM) alpha[b * KDIM + t] = ex / red[0];
}

// cs[b][h] = sum_k alpha[b][k] * iml[b][h][k]; one wave per row
__global__ void k_cs(const float* __restrict__ iml, const float* __restrict__ alpha,
                     float* __restrict__ cs) {
    int w = threadIdx.x >> 6, lane = threadIdx.x & 63;
    int row = blockIdx.x * 4 + w;
    int b = row >> 9;
    const float* p = iml + (size_t)row * KDIM;
    const float* al = alpha + b * KDIM;
    float s = p[lane] * al[lane] + p[lane + 64] * al[lane + 64] + p[lane + 128] * al[lane + 128]
            + ((lane < 4) ? p[lane + 192] * al[lane + 192] : 0.f);
#pragma unroll
    for (int off = 32; off; off >>= 1) s += __shfl_down(s, off);
    if (lane == 0) cs[row] = s;
}

// out[b*ostride + j] = relu(bias[j] + sum_i in[b][i] * W[j][i]); (64x512)@(512x512)
__global__ void k_dense_relu(const float* __restrict__ in, const float* __restrict__ W,
                             const float* __restrict__ bias, float* __restrict__ out, int ostride) {
    int b = blockIdx.y; int j = blockIdx.x * 256 + threadIdx.x;
    __shared__ float xs[512];
    xs[threadIdx.x] = in[b * 512 + threadIdx.x];
    xs[threadIdx.x + 256] = in[b * 512 + threadIdx.x + 256];
    __syncthreads();
    float acc = bias[j];
    const float4* w4 = (const float4*)(W + (size_t)j * 512);
#pragma unroll 4
    for (int i4 = 0; i4 < 128; ++i4) {
        float4 w = w4[i4];
        float4 x = *(const float4*)&xs[i4 * 4];
        acc += w.x * x.x + w.y * x.y + w.z * x.z + w.w * x.w;
    }
    out[(size_t)b * ostride + j] = fmaxf(acc, 0.f);
}

// xh[b][0:512] = img[b][:]
__global__ void k_init_xh(const float* __restrict__ img, float* __restrict__ xh) {
    int b = blockIdx.x, tid = threadIdx.x;   // 128 threads
    ((float4*)(xh + (size_t)b * 1024))[tid] = ((const float4*)(img + (size_t)b * 512))[tid];
}

// ---------------- the split-K GEMM (both LSTM and logits) ----------------
// part[(kc*64 + b)*wn + j] = sum_{kk<64} A[b*astride + kc*64+kk] * Wt[(kc*64+kk)*wn + j]
// grid (wn/256, K/64, 2); block 256 = 4 waves; wave covers 8 b x 256 j.
// blockIdx.x fastest & grid.x % 8 == 0  => blocks sharing a W-panel land on one XCD (L2 reuse).
__global__ void k_gemm_big(const float* __restrict__ A, int astride,
                           const float* __restrict__ Wt, int wn,
                           float* __restrict__ part) {
    int jb = blockIdx.x, kc = blockIdx.y, bh = blockIdx.z;
    int w = threadIdx.x >> 6, lane = threadIdx.x & 63;
    int b0 = __builtin_amdgcn_readfirstlane(bh * 32 + w * 8);   // SGPR => scalar x loads
    int k0 = kc * 64;
    int j0 = jb * 256 + lane * 4;
    float4 acc[8];
#pragma unroll
    for (int b = 0; b < 8; ++b) acc[b] = make_float4(0.f, 0.f, 0.f, 0.f);
    const float* wp = Wt + (size_t)k0 * wn + j0;
    const float* xp = A + (size_t)b0 * astride + k0;
#pragma unroll 8
    for (int kk = 0; kk < 64; ++kk) {
        float4 w4 = *(const float4*)(wp + (size_t)kk * wn);
#pragma unroll
        for (int b = 0; b < 8; ++b) {
            float xv = xp[(size_t)b * astride + kk];   // uniform address -> s_load
            acc[b].x += xv * w4.x; acc[b].y += xv * w4.y;
            acc[b].z += xv * w4.z; acc[b].w += xv * w4.w;
        }
    }
#pragma unroll
    for (int b = 0; b < 8; ++b)
        *(float4*)(part + (size_t)(kc * 64 + b0 + b) * wn + j0) = acc[b];
}

// ---------------- per-step finish kernels ----------------

// reduce 16 LSTM partials, biases+gates, write h into xh[:,512:] and c in place
__global__ void k_gates(const float* __restrict__ part, const float* __restrict__ bih,
                        const float* __restrict__ bhh, float* __restrict__ xh,
                        float* __restrict__ cbuf) {
    int e = blockIdx.x * 256 + threadIdx.x;   // e = b*512 + jj
    int b = e >> 9, jj = e & 511;
    float g[4];
#pragma unroll
    for (int gg = 0; gg < 4; ++gg) {
        int j = jj + gg * 512;
        float s = bih[j] + bhh[j];
#pragma unroll
        for (int c = 0; c < 16; ++c) s += part[(size_t)(c * 64 + b) * 2048 + j];
        g[gg] = s;
    }
    float ig = 1.f / (1.f + expf(-g[0]));
    float fg = 1.f / (1.f + expf(-g[1]));
    float gt = tanhf(g[2]);
    float og = 1.f / (1.f + expf(-g[3]));
    float c = fg * cbuf[e] + ig * gt;
    float h = og * tanhf(c);
    cbuf[e] = c;
    xh[(size_t)b * 1024 + 512 + jj] = h;
}

// base[b][v] = sum of 8 cs-logit partials + fc_b[v]   (v < V only)
__global__ void k_base_finish(const float* __restrict__ lpart, const float* __restrict__ fc_b,
                              float* __restrict__ base) {
    int b = blockIdx.y; int v = blockIdx.x * 256 + threadIdx.x;
    if (v < V) {
        float s = fc_b[v];
#pragma unroll
        for (int c = 0; c < 8; ++c) s += lpart[(size_t)(c * 64 + b) * VP + v];
        base[(size_t)b * VP + v] = s;
    }
}

// logits = sum 8 partials + base; write f32 out; per-(b,chunk) argmax partial
__global__ void k_logits_finish(const float* __restrict__ lpart, const float* __restrict__ base,
                                float* __restrict__ out0, float* __restrict__ amaxv,
                                int* __restrict__ amaxi, int t) {
    int b = blockIdx.y, vc = blockIdx.x, tid = threadIdx.x;
    int v = vc * 256 + tid;
    float val = -__builtin_inff();
    if (v < V) {
        float s = base[(size_t)b * VP + v];
#pragma unroll
        for (int c = 0; c < 8; ++c) s += lpart[(size_t)(c * 64 + b) * VP + v];
        out0[((size_t)b * TSTEPS + t) * V + v] = s;
        val = s;
    }
    __shared__ float sv[256]; __shared__ int si[256];
    sv[tid] = val; si[tid] = (v < V) ? v : 0x7fffffff;
    __syncthreads();
    for (int s = 128; s; s >>= 1) {
        if (tid < s) {
            if (sv[tid + s] > sv[tid] || (sv[tid + s] == sv[tid] && si[tid + s] < si[tid])) {
                sv[tid] = sv[tid + s]; si[tid] = si[tid + s];
            }
        }
        __syncthreads();
    }
    if (tid == 0) { amaxv[b * NVC + vc] = sv[0]; amaxi[b * NVC + vc] = si[0]; }
}

// final argmax per b + gather emb row into xh[b][0:512] + write sample
__global__ void k_argmax_gather(const float* __restrict__ amaxv, const int* __restrict__ amaxi,
                                const float* __restrict__ emb, float* __restrict__ xh,
                                float* __restrict__ out1, int t) {
    int b = blockIdx.x, tid = threadIdx.x;   // 128 threads
    __shared__ float sv[64]; __shared__ int si[64];
    if (tid < 64) {
        sv[tid] = (tid < NVC) ? amaxv[b * NVC + tid] : -__builtin_inff();
        si[tid] = (tid < NVC) ? amaxi[b * NVC + tid] : 0x7fffffff;
    }
    __syncthreads();
    for (int s = 32; s; s >>= 1) {
        if (tid < s) {
            if (sv[tid + s] > sv[tid] || (sv[tid + s] == sv[tid] && si[tid + s] < si[tid])) {
                sv[tid] = sv[tid + s]; si[tid] = si[tid + s];
            }
        }
        __syncthreads();
    }
    int bi = si[0];
    ((float4*)(xh + (size_t)b * 1024))[tid] = ((const float4*)(emb + (size_t)bi * 512))[tid];
    if (tid == 0) out1[b * TSTEPS + t] = (float)bi;
}

// ---------------- launch ----------------

extern "C" void kernel_launch(void* const* d_in, const int* in_sizes, int n_in,
                              void* d_out, int out_size, void* d_ws, size_t ws_size,
                              hipStream_t stream) {
    const float* iml   = (const float*)d_in[0];
    const float* img   = (const float*)d_in[1];
    const float* m1w1  = (const float*)d_in[2];
    const float* m1b1  = (const float*)d_in[3];
    const float* m1w2  = (const float*)d_in[4];
    const float* m1b2  = (const float*)d_in[5];
    const float* m2w1  = (const float*)d_in[6];
    const float* m2b1  = (const float*)d_in[7];
    const float* m2w2  = (const float*)d_in[8];
    const float* m2b2  = (const float*)d_in[9];
    const float* wih   = (const float*)d_in[10];
    const float* whh   = (const float*)d_in[11];
    const float* bih   = (const float*)d_in[12];
    const float* bhh   = (const float*)d_in[13];
    const float* attnw = (const float*)d_in[14];
    const float* fcw   = (const float*)d_in[16];
    const float* fcb   = (const float*)d_in[17];
    const float* emb   = (const float*)d_in[18];

    float* out0 = (float*)d_out;                        // logits (B, T, V) f32
    float* out1 = out0 + (size_t)B * TSTEPS * V;        // samples (B, T) as f32

    float* ws = (float*)d_ws;
    size_t off = 0;
    float* fcT   = ws + off; off += (size_t)512 * VP;        // 5.24M floats
    float* WcT   = ws + off; off += (size_t)1024 * 2048;     // 2.10M
    float* bigp  = ws + off; off += (size_t)8 * B * VP;      // 5.24M (aliases lstm 16x64x2048=2.10M)
    float* base  = ws + off; off += (size_t)B * VP;          // 0.66M
    float* xh    = ws + off; off += (size_t)B * 1024;
    float* meanb = ws + off; off += B * 512;
    float* alpha = ws + off; off += B * KDIM;
    float* csb   = ws + off; off += B * 512;
    float* tmpb  = ws + off; off += B * 512;
    float* cbuf  = ws + off; off += B * 512;
    float* amaxv = ws + off; off += B * NVC;
    int*   amaxi = (int*)(ws + off); off += B * NVC;

    // ---- precompute ----
    k_mean<<<dim3(8192), dim3(256), 0, stream>>>(iml, meanb);
    k_e_alpha<<<dim3(64), dim3(256), 0, stream>>>(iml, attnw, alpha);
    k_cs<<<dim3(8192), dim3(256), 0, stream>>>(iml, alpha, csb);
    k_dense_relu<<<dim3(2, 64), dim3(256), 0, stream>>>(meanb, m1w1, m1b1, tmpb, 512);
    k_dense_relu<<<dim3(2, 64), dim3(256), 0, stream>>>(tmpb, m1w2, m1b2, xh + 512, 1024);  // h0
    k_dense_relu<<<dim3(2, 64), dim3(256), 0, stream>>>(meanb, m2w1, m2b1, tmpb, 512);
    k_dense_relu<<<dim3(2, 64), dim3(256), 0, stream>>>(tmpb, m2w2, m2b2, cbuf, 512);       // c0
    k_init_xh<<<dim3(64), dim3(128), 0, stream>>>(img, xh);

    // base logits from cs using transpose of fc_w cols [512,1024)
    k_transpose_fc<<<dim3(VP / 32, 16), dim3(32, 8), 0, stream>>>(fcw, fcT, 512);
    k_gemm_big<<<dim3(40, 8, 2), dim3(256), 0, stream>>>(csb, 512, fcT, VP, bigp);
    k_base_finish<<<dim3(NVC, 64), dim3(256), 0, stream>>>(bigp, fcb, base);
    // now overwrite fcT with transpose of fc_w cols [0,512) for the step loop
    k_transpose_fc<<<dim3(VP / 32, 16), dim3(32, 8), 0, stream>>>(fcw, fcT, 0);
    k_build_wct<<<dim3(64, 32), dim3(32, 8), 0, stream>>>(wih, whh, WcT);

    // ---- decode loop ----
    for (int t = 0; t < TSTEPS; ++t) {
        k_gemm_big<<<dim3(8, 16, 2), dim3(256), 0, stream>>>(xh, 1024, WcT, 2048, bigp);
        k_gates<<<dim3(128), dim3(256), 0, stream>>>(bigp, bih, bhh, xh, cbuf);
        k_gemm_big<<<dim3(40, 8, 2), dim3(256), 0, stream>>>(xh + 512, 1024, fcT, VP, bigp);
        k_logits_finish<<<dim3(NVC, 64), dim3(256), 0, stream>>>(bigp, base, out0, amaxv, amaxi, t);
        k_argmax_gather<<<dim3(64), dim3(128), 0, stream>>>(amaxv, amaxi, emb, xh, out1, t);
    }
}